// Round 1
// baseline (207.135 us; speedup 1.0000x reference)
//
#include <hip/hip_runtime.h>
#include <math.h>

#define BATCH 32
#define CH 3
#define HH 256
#define WW 256
#define PP 32
#define NPATCH 4

// ---------------- pool: pooled(b,c,8,8) = mean over 32x32 blocks -> feat[b,192]
__global__ __launch_bounds__(256) void pool_kernel(const float* __restrict__ x,
                                                   float* __restrict__ feat) {
  int wave = threadIdx.x >> 6;
  int lane = threadIdx.x & 63;
  int cell = blockIdx.x * 4 + wave;            // 0..6143 = b*192 + c*64 + i*8 + j
  int b = cell / 192;
  int rem = cell % 192;
  int c = rem >> 6;
  int ij = rem & 63;
  int i = ij >> 3, j = ij & 7;
  const float* base = x + ((size_t)(b * CH + c)) * HH * WW;
  int dr = lane >> 5, dc = lane & 31;
  int col = j * 32 + dc;
  float s = 0.f;
#pragma unroll
  for (int it = 0; it < 16; ++it) {
    int row = i * 32 + it * 2 + dr;
    s += base[row * WW + col];
  }
#pragma unroll
  for (int m = 32; m >= 1; m >>= 1) s += __shfl_xor(s, m, 64);
  if (lane == 0) feat[cell] = s * (1.f / 1024.f);
}

// ---------------- mlp: hmid = relu(feat@pw1^T+pb1); pos = sigmoid(hmid@pw2^T+pb2)
// posw[b*8 + p*2 + 0] = floor(pos_y*224), +1 = floor(pos_x*224)
__global__ __launch_bounds__(128) void mlp_kernel(const float* __restrict__ feat,
                                                  const float* __restrict__ pw1,
                                                  const float* __restrict__ pb1,
                                                  const float* __restrict__ pw2,
                                                  const float* __restrict__ pb2,
                                                  int* __restrict__ posw) {
  int b = blockIdx.x;
  int t = threadIdx.x;
  __shared__ float fs[192];
  __shared__ float hs[128];
  for (int k = t; k < 192; k += 128) fs[k] = feat[b * 192 + k];
  __syncthreads();
  float a = pb1[t];
  for (int k = 0; k < 192; ++k) a = fmaf(fs[k], pw1[t * 192 + k], a);
  hs[t] = fmaxf(a, 0.f);
  __syncthreads();
  if (t < 8) {
    float a2 = pb2[t];
    for (int k = 0; k < 128; ++k) a2 = fmaf(hs[k], pw2[t * 128 + k], a2);
    float sgm = 1.f / (1.f + expf(-a2));
    posw[b * 8 + t] = (int)floorf(sgm * (float)(HH - PP));
  }
}

// ---------------- copy x -> out (vectorized)
__global__ __launch_bounds__(256) void copy_kernel(const float4* __restrict__ src,
                                                   float4* __restrict__ dst, int n4) {
  int i = blockIdx.x * 256 + threadIdx.x;
  if (i < n4) dst[i] = src[i];
}

// ---------------- patch: per (b,p) block, compute patches window and atomicAdd into out
__global__ __launch_bounds__(256) void patch_kernel(
    const float* __restrict__ x, const float* __restrict__ w1,
    const float* __restrict__ b1, const float* __restrict__ w2,
    const float* __restrict__ b2, const float* __restrict__ w3,
    const float* __restrict__ b3, const int* __restrict__ posw,
    float* __restrict__ out) {
  const int blk = blockIdx.x;
  const int b = blk >> 2, p = blk & 3;
  const int y0 = posw[b * 8 + p * 2 + 0];
  const int x0 = posw[b * 8 + p * 2 + 1];
  const int t = threadIdx.x;

  __shared__ float xs[3][38 * 38];   // x window [y0-3, y0+34]
  __shared__ float h1c[36 * 36];     // one h1 channel, [y0-2, y0+33]
  __shared__ float h2s[16][34 * 34]; // h2, [y0-1, y0+32]

  // stage 0: load x window with zero pad
  for (int idx = t; idx < 3 * 38 * 38; idx += 256) {
    int c = idx / (38 * 38);
    int r = idx - c * (38 * 38);
    int ky = r / 38, kx = r - (r / 38) * 38;
    int gy = y0 - 3 + ky, gx = x0 - 3 + kx;
    float v = 0.f;
    if ((unsigned)gy < 256u && (unsigned)gx < 256u)
      v = x[((size_t)(b * 3 + c) * 256 + gy) * 256 + gx];
    xs[c][ky * 38 + kx] = v;
  }
  __syncthreads();

  // per-thread h2 positions (5 strided positions over 34x34 = 1156)
  int iyv[5], ixv[5];
  bool valid[5], inimg[5];
#pragma unroll
  for (int r = 0; r < 5; ++r) {
    int idx = t + 256 * r;
    valid[r] = (idx < 34 * 34);
    int ic = valid[r] ? idx : 0;
    iyv[r] = ic / 34;
    ixv[r] = ic - iyv[r] * 34;
    int gy = y0 - 1 + iyv[r], gx = x0 - 1 + ixv[r];
    inimg[r] = ((unsigned)gy < 256u) && ((unsigned)gx < 256u);
  }

  float acc[16][5];
#pragma unroll
  for (int c2 = 0; c2 < 16; ++c2)
#pragma unroll
    for (int r = 0; r < 5; ++r) acc[c2][r] = 0.f;

  for (int c1 = 0; c1 < 32; ++c1) {
    // h1 channel c1 (zero outside image: SAME padding semantics at next conv)
#pragma unroll
    for (int rr = 0; rr < 6; ++rr) {
      int idx = t + 256 * rr;
      if (idx < 36 * 36) {
        int jy = idx / 36, jx = idx - (idx / 36) * 36;
        int gy = y0 - 2 + jy, gx = x0 - 2 + jx;
        float v = 0.f;
        if ((unsigned)gy < 256u && (unsigned)gx < 256u) {
          float s = b1[c1];
#pragma unroll
          for (int c = 0; c < 3; ++c)
#pragma unroll
            for (int dy = 0; dy < 3; ++dy)
#pragma unroll
              for (int dx = 0; dx < 3; ++dx)
                s = fmaf(w1[((c1 * 3 + c) * 3 + dy) * 3 + dx],
                         xs[c][(jy + dy) * 38 + (jx + dx)], s);
          v = fmaxf(s, 0.f);
        }
        h1c[idx] = v;
      }
    }
    __syncthreads();

    // accumulate h2 in registers
    float hw[5][9];
#pragma unroll
    for (int r = 0; r < 5; ++r)
#pragma unroll
      for (int dy = 0; dy < 3; ++dy)
#pragma unroll
        for (int dx = 0; dx < 3; ++dx)
          hw[r][dy * 3 + dx] = h1c[(iyv[r] + dy) * 36 + (ixv[r] + dx)];
#pragma unroll
    for (int c2 = 0; c2 < 16; ++c2) {
#pragma unroll
      for (int k = 0; k < 9; ++k) {
        float w = w2[(c2 * 32 + c1) * 9 + k];
#pragma unroll
        for (int r = 0; r < 5; ++r) acc[c2][r] = fmaf(w, hw[r][k], acc[c2][r]);
      }
    }
    __syncthreads();  // before next c1 overwrites h1c
  }

  // write h2 (bias + relu, zero outside image)
#pragma unroll
  for (int c2 = 0; c2 < 16; ++c2)
#pragma unroll
    for (int r = 0; r < 5; ++r)
      if (valid[r]) {
        float v = fmaxf(acc[c2][r] + b2[c2], 0.f);
        h2s[c2][iyv[r] * 34 + ixv[r]] = inimg[r] ? v : 0.f;
      }
  __syncthreads();

  // final conv (3 out ch) + tanh*0.1 + atomicAdd into out
#pragma unroll
  for (int r2 = 0; r2 < 4; ++r2) {
    int oidx = t + 256 * r2;
    int oy = oidx >> 5, ox = oidx & 31;
    float a0 = b3[0], a1 = b3[1], a2 = b3[2];
    for (int c2 = 0; c2 < 16; ++c2) {
#pragma unroll
      for (int dy = 0; dy < 3; ++dy)
#pragma unroll
        for (int dx = 0; dx < 3; ++dx) {
          float h = h2s[c2][(oy + dy) * 34 + (ox + dx)];
          a0 = fmaf(w3[(0 * 16 + c2) * 9 + dy * 3 + dx], h, a0);
          a1 = fmaf(w3[(1 * 16 + c2) * 9 + dy * 3 + dx], h, a1);
          a2 = fmaf(w3[(2 * 16 + c2) * 9 + dy * 3 + dx], h, a2);
        }
    }
    int gy = y0 + oy, gx = x0 + ox;
    atomicAdd(&out[((size_t)(b * 3 + 0) * 256 + gy) * 256 + gx], tanhf(a0) * 0.1f);
    atomicAdd(&out[((size_t)(b * 3 + 1) * 256 + gy) * 256 + gx], tanhf(a1) * 0.1f);
    atomicAdd(&out[((size_t)(b * 3 + 2) * 256 + gy) * 256 + gx], tanhf(a2) * 0.1f);
  }
}

extern "C" void kernel_launch(void* const* d_in, const int* in_sizes, int n_in,
                              void* d_out, int out_size, void* d_ws, size_t ws_size,
                              hipStream_t stream) {
  const float* x   = (const float*)d_in[0];
  const float* w1  = (const float*)d_in[1];
  const float* b1  = (const float*)d_in[2];
  const float* w2  = (const float*)d_in[3];
  const float* b2  = (const float*)d_in[4];
  const float* w3  = (const float*)d_in[5];
  const float* b3  = (const float*)d_in[6];
  const float* pw1 = (const float*)d_in[7];
  const float* pb1 = (const float*)d_in[8];
  const float* pw2 = (const float*)d_in[9];
  const float* pb2 = (const float*)d_in[10];
  float* out = (float*)d_out;

  float* feat = (float*)d_ws;                                  // 6144 floats
  int* posw = (int*)((char*)d_ws + 6144 * sizeof(float));      // 256 ints

  pool_kernel<<<1536, 256, 0, stream>>>(x, feat);
  mlp_kernel<<<BATCH, 128, 0, stream>>>(feat, pw1, pb1, pw2, pb2, posw);
  int n4 = (BATCH * CH * HH * WW) / 4;
  copy_kernel<<<(n4 + 255) / 256, 256, 0, stream>>>((const float4*)x, (float4*)out, n4);
  patch_kernel<<<BATCH * NPATCH, 256, 0, stream>>>(x, w1, b1, w2, b2, w3, b3, posw, out);
}

// Round 2
// 134.716 us; speedup vs baseline: 1.5376x; 1.5376x over previous
//
#include <hip/hip_runtime.h>
#include <math.h>

#define BATCH 32
#define CH 3
#define HH 256
#define WW 256
#define PP 32
#define NPATCH 4

// ---------------- pool: pooled(b,c,8,8) = mean over 32x32 blocks -> feat[b,192]
__global__ __launch_bounds__(256) void pool_kernel(const float* __restrict__ x,
                                                   float* __restrict__ feat) {
  int wave = threadIdx.x >> 6;
  int lane = threadIdx.x & 63;
  int cell = blockIdx.x * 4 + wave;            // 0..6143 = b*192 + c*64 + i*8 + j
  int b = cell / 192;
  int rem = cell % 192;
  int c = rem >> 6;
  int ij = rem & 63;
  int i = ij >> 3, j = ij & 7;
  const float* base = x + ((size_t)(b * CH + c)) * HH * WW;
  int dr = lane >> 5, dc = lane & 31;
  int col = j * 32 + dc;
  float s = 0.f;
#pragma unroll
  for (int it = 0; it < 16; ++it) {
    int row = i * 32 + it * 2 + dr;
    s += base[row * WW + col];
  }
#pragma unroll
  for (int m = 32; m >= 1; m >>= 1) s += __shfl_xor(s, m, 64);
  if (lane == 0) feat[cell] = s * (1.f / 1024.f);
}

// ---------------- mlp: hmid = relu(feat@pw1^T+pb1); pos = sigmoid(hmid@pw2^T+pb2)
__global__ __launch_bounds__(128) void mlp_kernel(const float* __restrict__ feat,
                                                  const float* __restrict__ pw1,
                                                  const float* __restrict__ pb1,
                                                  const float* __restrict__ pw2,
                                                  const float* __restrict__ pb2,
                                                  int* __restrict__ posw) {
  int b = blockIdx.x;
  int t = threadIdx.x;
  __shared__ float fs[192];
  __shared__ float hs[128];
  for (int k = t; k < 192; k += 128) fs[k] = feat[b * 192 + k];
  __syncthreads();
  float a = pb1[t];
  for (int k = 0; k < 192; ++k) a = fmaf(fs[k], pw1[t * 192 + k], a);
  hs[t] = fmaxf(a, 0.f);
  __syncthreads();
  if (t < 8) {
    float a2 = pb2[t];
    for (int k = 0; k < 128; ++k) a2 = fmaf(hs[k], pw2[t * 128 + k], a2);
    float sgm = 1.f / (1.f + expf(-a2));
    posw[b * 8 + t] = (int)floorf(sgm * (float)(HH - PP));
  }
}

// ---------------- copy x -> out (vectorized)
__global__ __launch_bounds__(256) void copy_kernel(const float4* __restrict__ src,
                                                   float4* __restrict__ dst, int n4) {
  int i = blockIdx.x * 256 + threadIdx.x;
  if (i < n4) dst[i] = src[i];
}

// ---------------- patch: per (b,p,subtile) block: 32x8 output rows
// subtile s covers patch-local output rows [s*8, s*8+8)
// tiles (local frames):
//   h2: rows s*8-1 .. s*8+9   (10) x 34 cols
//   h1: rows s*8-2 .. s*8+10  (12) x 36 cols
//   x : rows s*8-3 .. s*8+11  (14) x 38 cols
__global__ __launch_bounds__(256) void patch_kernel(
    const float* __restrict__ x, const float* __restrict__ w1,
    const float* __restrict__ b1, const float* __restrict__ w2,
    const float* __restrict__ b2, const float* __restrict__ w3,
    const float* __restrict__ b3, const int* __restrict__ posw,
    float* __restrict__ out) {
  const int blk = blockIdx.x;
  const int s = blk & 3;
  const int p = (blk >> 2) & 3;
  const int b = blk >> 4;
  const int y0 = posw[b * 8 + p * 2 + 0];
  const int x0 = posw[b * 8 + p * 2 + 1];
  const int t = threadIdx.x;
  const int rowbase = s * 8;

  __shared__ float xs[3][14 * 38];    // 1596 f
  __shared__ float h1s[8][12 * 36];   // 3456 f (one c1-chunk)
  __shared__ float h2s[16][10 * 34];  // 5440 f

  // stage x window (zero-padded)
  for (int idx = t; idx < 3 * 14 * 38; idx += 256) {
    int c = idx / (14 * 38);
    int r = idx - c * (14 * 38);
    int ky = r / 38, kx = r - (r / 38) * 38;
    int gy = y0 + rowbase - 3 + ky, gx = x0 - 3 + kx;
    float v = 0.f;
    if ((unsigned)gy < 256u && (unsigned)gx < 256u)
      v = x[((size_t)(b * 3 + c) * 256 + gy) * 256 + gx];
    xs[c][ky * 38 + kx] = v;
  }

  // per-thread h2 positions (2 strided over 10*34=340)
  int iyv[2], ixv[2];
  bool valid[2], inimg[2];
#pragma unroll
  for (int r = 0; r < 2; ++r) {
    int idx = t + 256 * r;
    valid[r] = idx < 340;
    int ic = valid[r] ? idx : 0;
    iyv[r] = ic / 34;
    ixv[r] = ic - iyv[r] * 34;
    int gy = y0 + rowbase - 1 + iyv[r], gx = x0 - 1 + ixv[r];
    inimg[r] = ((unsigned)gy < 256u) && ((unsigned)gx < 256u);
  }

  // per-thread h1 positions (2 strided over 12*36=432)
  int jyv[2], jxv[2];
  bool h1w[2], h1in[2];
#pragma unroll
  for (int r = 0; r < 2; ++r) {
    int idx = t + 256 * r;
    h1w[r] = idx < 432;
    int ic = h1w[r] ? idx : 0;
    jyv[r] = ic / 36;
    jxv[r] = ic - jyv[r] * 36;
    int gy = y0 + rowbase - 2 + jyv[r], gx = x0 - 2 + jxv[r];
    h1in[r] = ((unsigned)gy < 256u) && ((unsigned)gx < 256u);
  }

  float acc[16][2];
#pragma unroll
  for (int c2 = 0; c2 < 16; ++c2) {
    acc[c2][0] = 0.f;
    acc[c2][1] = 0.f;
  }
  __syncthreads();

  for (int chunk = 0; chunk < 4; ++chunk) {
    // h1 for 8 channels of this chunk (uniform control flow; guarded writes)
#pragma unroll
    for (int rr = 0; rr < 2; ++rr) {
      float xw[27];
#pragma unroll
      for (int c = 0; c < 3; ++c)
#pragma unroll
        for (int dy = 0; dy < 3; ++dy)
#pragma unroll
          for (int dx = 0; dx < 3; ++dx)
            xw[(c * 3 + dy) * 3 + dx] = xs[c][(jyv[rr] + dy) * 38 + (jxv[rr] + dx)];
#pragma unroll
      for (int cc = 0; cc < 8; ++cc) {
        int c1 = chunk * 8 + cc;
        float ssum = b1[c1];
#pragma unroll
        for (int k = 0; k < 27; ++k) ssum = fmaf(w1[c1 * 27 + k], xw[k], ssum);
        if (h1w[rr])
          h1s[cc][jyv[rr] * 36 + jxv[rr]] = h1in[rr] ? fmaxf(ssum, 0.f) : 0.f;
      }
    }
    __syncthreads();

    // h2 accumulate over the chunk's 8 channels
#pragma unroll
    for (int cc = 0; cc < 8; ++cc) {
      int c1 = chunk * 8 + cc;
      float hw[2][9];
#pragma unroll
      for (int r = 0; r < 2; ++r)
#pragma unroll
        for (int dy = 0; dy < 3; ++dy)
#pragma unroll
          for (int dx = 0; dx < 3; ++dx)
            hw[r][dy * 3 + dx] = h1s[cc][(iyv[r] + dy) * 36 + (ixv[r] + dx)];
#pragma unroll
      for (int c2 = 0; c2 < 16; ++c2) {
#pragma unroll
        for (int k = 0; k < 9; ++k) {
          float w = w2[(c2 * 32 + c1) * 9 + k];
          acc[c2][0] = fmaf(w, hw[0][k], acc[c2][0]);
          acc[c2][1] = fmaf(w, hw[1][k], acc[c2][1]);
        }
      }
    }
    __syncthreads();
  }

  // write h2 (bias + relu; zero outside image)
#pragma unroll
  for (int c2 = 0; c2 < 16; ++c2)
#pragma unroll
    for (int r = 0; r < 2; ++r)
      if (valid[r]) {
        float v = fmaxf(acc[c2][r] + b2[c2], 0.f);
        h2s[c2][iyv[r] * 34 + ixv[r]] = inimg[r] ? v : 0.f;
      }
  __syncthreads();

  // final conv (3 out ch) + tanh*0.1 + atomicAdd; one output pixel per thread
  {
    int oy = t >> 5, ox = t & 31;
    float a0 = b3[0], a1 = b3[1], a2 = b3[2];
#pragma unroll
    for (int c2 = 0; c2 < 16; ++c2) {
#pragma unroll
      for (int dy = 0; dy < 3; ++dy)
#pragma unroll
        for (int dx = 0; dx < 3; ++dx) {
          float h = h2s[c2][(oy + dy) * 34 + (ox + dx)];
          a0 = fmaf(w3[(0 * 16 + c2) * 9 + dy * 3 + dx], h, a0);
          a1 = fmaf(w3[(1 * 16 + c2) * 9 + dy * 3 + dx], h, a1);
          a2 = fmaf(w3[(2 * 16 + c2) * 9 + dy * 3 + dx], h, a2);
        }
    }
    int gy = y0 + rowbase + oy, gx = x0 + ox;
    atomicAdd(&out[((size_t)(b * 3 + 0) * 256 + gy) * 256 + gx], tanhf(a0) * 0.1f);
    atomicAdd(&out[((size_t)(b * 3 + 1) * 256 + gy) * 256 + gx], tanhf(a1) * 0.1f);
    atomicAdd(&out[((size_t)(b * 3 + 2) * 256 + gy) * 256 + gx], tanhf(a2) * 0.1f);
  }
}

extern "C" void kernel_launch(void* const* d_in, const int* in_sizes, int n_in,
                              void* d_out, int out_size, void* d_ws, size_t ws_size,
                              hipStream_t stream) {
  const float* x   = (const float*)d_in[0];
  const float* w1  = (const float*)d_in[1];
  const float* b1  = (const float*)d_in[2];
  const float* w2  = (const float*)d_in[3];
  const float* b2  = (const float*)d_in[4];
  const float* w3  = (const float*)d_in[5];
  const float* b3  = (const float*)d_in[6];
  const float* pw1 = (const float*)d_in[7];
  const float* pb1 = (const float*)d_in[8];
  const float* pw2 = (const float*)d_in[9];
  const float* pb2 = (const float*)d_in[10];
  float* out = (float*)d_out;

  float* feat = (float*)d_ws;                                  // 6144 floats
  int* posw = (int*)((char*)d_ws + 6144 * sizeof(float));      // 256 ints

  pool_kernel<<<1536, 256, 0, stream>>>(x, feat);
  mlp_kernel<<<BATCH, 128, 0, stream>>>(feat, pw1, pb1, pw2, pb2, posw);
  int n4 = (BATCH * CH * HH * WW) / 4;
  copy_kernel<<<(n4 + 255) / 256, 256, 0, stream>>>((const float4*)x, (float4*)out, n4);
  patch_kernel<<<BATCH * NPATCH * 4, 256, 0, stream>>>(x, w1, b1, w2, b2, w3, b3, posw, out);
}